// Round 8
// baseline (171.415 us; speedup 1.0000x reference)
//
#include <hip/hip_runtime.h>
#include <math.h>

#define B  128
#define T  1024
#define DM 512
#define DQ 1024
#define DA 128
#define F  32
#define KW 31
#define TSEG 4

typedef short s16x8 __attribute__((ext_vector_type(8)));
typedef float f32x4 __attribute__((ext_vector_type(4)));
typedef unsigned int u32;
typedef u32 u32x4 __attribute__((ext_vector_type(4)));

__device__ __forceinline__ unsigned short f2bf(float f) {   // RNE
    u32 u = __builtin_bit_cast(u32, f);
    u32 r = u + 0x7FFFu + ((u >> 16) & 1u);
    return (unsigned short)(r >> 16);
}
__device__ __forceinline__ float bf2f(unsigned short h) {
    u32 u = ((u32)h) << 16;
    return __builtin_bit_cast(float, u);
}
__device__ __forceinline__ float fast_tanh(float x) {
    float ax = fabsf(x);
    float e = __expf(-2.0f * ax);
    float t = 1.0f - 2.0f * e / (1.0f + e);
    return copysignf(t, x);
}

// truncate-split: hi = f with low 16 mantissa bits zeroed (exact bf16), lo = f - hi
// (exact in f32), lo truncated to bf16. Residual ~2^-16 rel.
__device__ __forceinline__ void trunc_split_pack(f32x4 a, f32x4 b, s16x8& hi, s16x8& lo) {
    u32x4 hw, lw;
    #pragma unroll
    for (int p = 0; p < 4; ++p) {
        float f0 = (p < 2) ? a[2 * p] : b[2 * p - 4];
        float f1 = (p < 2) ? a[2 * p + 1] : b[2 * p - 3];
        u32 u0 = __builtin_bit_cast(u32, f0);
        u32 u1 = __builtin_bit_cast(u32, f1);
        u32 t0 = u0 & 0xFFFF0000u;
        u32 t1 = u1 & 0xFFFF0000u;
        float l0 = f0 - __builtin_bit_cast(float, t0);
        float l1 = f1 - __builtin_bit_cast(float, t1);
        hw[p] = (u0 >> 16) | t1;
        lw[p] = (__builtin_bit_cast(u32, l0) >> 16) | (__builtin_bit_cast(u32, l1) & 0xFFFF0000u);
    }
    hi = __builtin_bit_cast(s16x8, hw);
    lo = __builtin_bit_cast(s16x8, lw);
}

// ---------------- prep: pq partials (4-way DQ split), Wmem hi (transposed, linear), CWt ----------------
__global__ __launch_bounds__(128) void prep_kernel(
        const float* __restrict__ query, const float* __restrict__ Wq,
        const float* __restrict__ Wmem, const float* __restrict__ conv_k,
        const float* __restrict__ Wloc,
        float* __restrict__ pqp, unsigned short* __restrict__ wsplit,
        unsigned short* __restrict__ CWt) {
    int a = threadIdx.x;
    int blk = blockIdx.x;
    if (blk < 4 * B) {
        int b = blk >> 2, q = blk & 3;
        const float* qp = query + b * DQ + q * 256;
        const float* wp = Wq + (size_t)(q * 256) * DA + a;
        float s = 0.f;
        #pragma unroll 4
        for (int i = 0; i < 256; ++i) s += qp[i] * wp[(size_t)i * DA];
        pqp[(q * B + b) * DA + a] = s;
    } else if (blk < 4 * B + DM) {
        int k = blk - 4 * B;
        unsigned short hi = f2bf(Wmem[k * DA + a]);   // B_hi only
        int c = k >> 6;
        wsplit[c * 8192 + a * 64 + (k & 63)] = hi;    // [chunk][a][k] linear (no swizzle)
    } else {
        int k = blk - (4 * B + DM);                   // 0..31 (row 31 = zero pad)
        float s = 0.f;
        if (k < KW) {
            #pragma unroll
            for (int f = 0; f < F; ++f) s += conv_k[k * F + f] * Wloc[f * DA + a];
        }
        CWt[a * 32 + k] = f2bf(s);                    // [a][k] contiguous
    }
}

// ---------------- energy via bf16 MFMA: barrier-free K-loop, B direct from L2 ----------------
__global__ __launch_bounds__(256, 2) void energy_mfma(
        const float* __restrict__ memory, const float* __restrict__ state,
        const float* __restrict__ pqp, const unsigned short* __restrict__ wsplit,
        const unsigned short* __restrict__ CWt, const float* __restrict__ v_w,
        const float* __restrict__ v_b, float* __restrict__ energy) {
    __shared__ float stl[160];
    __shared__ float pql[DA];
    __shared__ float vwl[DA];

    int tid = threadIdx.x;
    int w = tid >> 6, l = tid & 63, r = l & 15, g = l >> 4;
    int b  = blockIdx.x >> 3;
    int t0 = (blockIdx.x & 7) << 7;          // 128-row tile

    for (int i = tid; i < 160; i += 256) {
        int t = t0 - 15 + i;
        stl[i] = (i < 159 && t >= 0 && t < T) ? state[b * T + t] : 0.f;
    }
    if (tid < DA) {
        float s = 0.f;
        #pragma unroll
        for (int q = 0; q < 4; ++q) s += pqp[(q * B + b) * DA + tid];
        pql[tid] = s;
        vwl[tid] = v_w[tid];
    }
    __syncthreads();                          // the only barrier

    f32x4 acc0[8], acc1[8];
    #pragma unroll
    for (int nt = 0; nt < 8; ++nt) {
        acc0[nt] = (f32x4){0.f, 0.f, 0.f, 0.f};
        acc1[nt] = (f32x4){0.f, 0.f, 0.f, 0.f};
    }

    const size_t arow = ((size_t)(b * T + t0 + w * 32 + r)) * DM;
    const float* Abase = memory + arow + g * 8;
    const unsigned short* Bbase = wsplit + r * 64 + g * 8;   // + c*8192 + nt*1024 + kk*32

    f32x4 rA[8], rAn[8];
    {   // prologue A(0)
        const float* p = Abase;
        #pragma unroll
        for (int kk = 0; kk < 2; ++kk) {
            rA[kk * 4 + 0] = *(const f32x4*)(p + kk * 32);
            rA[kk * 4 + 1] = *(const f32x4*)(p + kk * 32 + 4);
            rA[kk * 4 + 2] = *(const f32x4*)(p + kk * 32 + 16 * DM);
            rA[kk * 4 + 3] = *(const f32x4*)(p + kk * 32 + 16 * DM + 4);
        }
    }

    for (int c = 0; c < 8; ++c) {
        if (c < 7) {   // prefetch next chunk's A into registers (hides HBM latency)
            const float* p = Abase + (c + 1) * 64;
            #pragma unroll
            for (int kk = 0; kk < 2; ++kk) {
                rAn[kk * 4 + 0] = *(const f32x4*)(p + kk * 32);
                rAn[kk * 4 + 1] = *(const f32x4*)(p + kk * 32 + 4);
                rAn[kk * 4 + 2] = *(const f32x4*)(p + kk * 32 + 16 * DM);
                rAn[kk * 4 + 3] = *(const f32x4*)(p + kk * 32 + 16 * DM + 4);
            }
        }
        const unsigned short* Bc = Bbase + c * 8192;
        #pragma unroll
        for (int kk = 0; kk < 2; ++kk) {
            s16x8 Ah0, Al0, Ah1, Al1;
            trunc_split_pack(rA[kk * 4 + 0], rA[kk * 4 + 1], Ah0, Al0);
            trunc_split_pack(rA[kk * 4 + 2], rA[kk * 4 + 3], Ah1, Al1);
            s16x8 Bv[8];
            #pragma unroll
            for (int nt = 0; nt < 8; ++nt)
                Bv[nt] = *(const s16x8*)(Bc + nt * 1024 + kk * 32);   // L2-hot, coalesced 2KB/wave
            #pragma unroll
            for (int nt = 0; nt < 8; ++nt) {
                acc0[nt] = __builtin_amdgcn_mfma_f32_16x16x32_bf16(Ah0, Bv[nt], acc0[nt], 0, 0, 0);
                acc0[nt] = __builtin_amdgcn_mfma_f32_16x16x32_bf16(Al0, Bv[nt], acc0[nt], 0, 0, 0);
                acc1[nt] = __builtin_amdgcn_mfma_f32_16x16x32_bf16(Ah1, Bv[nt], acc1[nt], 0, 0, 0);
                acc1[nt] = __builtin_amdgcn_mfma_f32_16x16x32_bf16(Al1, Bv[nt], acc1[nt], 0, 0, 0);
            }
        }
        #pragma unroll
        for (int j = 0; j < 8; ++j) rA[j] = rAn[j];
    }

    // ---- fold loc conv into the accumulators (CWt direct from L2) ----
    s16x8 st0, st1;
    {
        int base0 = w * 32 + r + g * 8;
        #pragma unroll
        for (int j = 0; j < 8; ++j) {
            st0[j] = (short)f2bf(stl[base0 + j]);
            st1[j] = (short)f2bf(stl[base0 + 16 + j]);
        }
    }
    #pragma unroll
    for (int nt = 0; nt < 8; ++nt) {
        s16x8 cw = *(const s16x8*)(CWt + (nt * 16 + r) * 32 + g * 8);
        acc0[nt] = __builtin_amdgcn_mfma_f32_16x16x32_bf16(st0, cw, acc0[nt], 0, 0, 0);
        acc1[nt] = __builtin_amdgcn_mfma_f32_16x16x32_bf16(st1, cw, acc1[nt], 0, 0, 0);
    }

    // ---- epilogue: +pq, tanh, .v_w, 16-lane reduce, write energy ----
    float vb = *v_b;
    #pragma unroll
    for (int sub = 0; sub < 2; ++sub) {
        #pragma unroll
        for (int reg = 0; reg < 4; ++reg) {
            float p = 0.f;
            #pragma unroll
            for (int nt = 0; nt < 8; ++nt) {
                int col = nt * 16 + r;
                float v = (sub == 0) ? acc0[nt][reg] : acc1[nt][reg];
                p += fast_tanh(v + pql[col]) * vwl[col];
            }
            p += __shfl_xor(p, 1, 16);
            p += __shfl_xor(p, 2, 16);
            p += __shfl_xor(p, 4, 16);
            p += __shfl_xor(p, 8, 16);
            if (r == 0)
                energy[b * T + t0 + w * 32 + sub * 16 + g * 4 + reg] = p + vb;
        }
    }
}

// ---------------- fused softmax + context partials ----------------
__global__ __launch_bounds__(256) void softmax_context_kernel(
        const float* __restrict__ energy, const float* __restrict__ state,
        const float* __restrict__ memory,
        float* __restrict__ alignments, float* __restrict__ new_state,
        float* __restrict__ partial) {
    int b = blockIdx.x, seg = blockIdx.y, tid = threadIdx.x;
    __shared__ float rmax[4], rsum[4];
    __shared__ float al[T / TSEG];
    __shared__ f32x4 comb[128];

    f32x4 ev = ((const f32x4*)(energy + b * T))[tid];
    float m = fmaxf(fmaxf(ev[0], ev[1]), fmaxf(ev[2], ev[3]));
    #pragma unroll
    for (int off = 32; off > 0; off >>= 1) m = fmaxf(m, __shfl_xor(m, off, 64));
    if ((tid & 63) == 0) rmax[tid >> 6] = m;
    __syncthreads();
    m = fmaxf(fmaxf(rmax[0], rmax[1]), fmaxf(rmax[2], rmax[3]));
    f32x4 x;
    x[0] = __expf(ev[0] - m); x[1] = __expf(ev[1] - m);
    x[2] = __expf(ev[2] - m); x[3] = __expf(ev[3] - m);
    float s = x[0] + x[1] + x[2] + x[3];
    #pragma unroll
    for (int off = 32; off > 0; off >>= 1) s += __shfl_xor(s, off, 64);
    if ((tid & 63) == 0) rsum[tid >> 6] = s;
    __syncthreads();
    s = rsum[0] + rsum[1] + rsum[2] + rsum[3];
    float inv = 1.0f / s;
    f32x4 a4 = x * inv;
    if ((tid >> 6) == seg) {                      // own this seg's slice
        ((f32x4*)al)[tid & 63] = a4;
        ((f32x4*)(alignments + b * T))[tid] = a4;
        f32x4 st4 = ((const f32x4*)(state + b * T))[tid];
        ((f32x4*)(new_state + b * T))[tid] = a4 + st4;
    }
    __syncthreads();

    int half = tid >> 7;
    int dg = tid & 127;
    const float* memB = memory + ((size_t)b * T + seg * (T / TSEG)) * DM;
    f32x4 acc = (f32x4){0.f, 0.f, 0.f, 0.f};
    #pragma unroll 4
    for (int it = 0; it < 128; ++it) {
        int t = it * 2 + half;
        float a = al[t];
        f32x4 v = *(const f32x4*)(memB + (size_t)t * DM + dg * 4);
        acc += v * a;
    }
    if (half) comb[dg] = acc;
    __syncthreads();
    if (!half) {
        acc += comb[dg];
        ((f32x4*)(partial + ((size_t)seg * B + b) * DM))[dg] = acc;
    }
}

__global__ __launch_bounds__(256) void context_reduce_kernel(
        const float* __restrict__ partial, float* __restrict__ context) {
    int b = blockIdx.x;
    int tid = threadIdx.x;
    #pragma unroll
    for (int j = 0; j < 2; ++j) {
        int d = tid + j * 256;
        float s = 0.f;
        #pragma unroll
        for (int g = 0; g < TSEG; ++g) s += partial[((size_t)g * B + b) * DM + d];
        context[b * DM + d] = s;
    }
}

extern "C" void kernel_launch(void* const* d_in, const int* in_sizes, int n_in,
                              void* d_out, int out_size, void* d_ws, size_t ws_size,
                              hipStream_t stream) {
    const float* query  = (const float*)d_in[0];
    const float* state  = (const float*)d_in[1];
    const float* memory = (const float*)d_in[3];
    const float* Wq     = (const float*)d_in[4];
    const float* Wmem   = (const float*)d_in[5];
    const float* conv_k = (const float*)d_in[6];
    const float* Wloc   = (const float*)d_in[7];
    const float* v_w    = (const float*)d_in[8];
    const float* v_b    = (const float*)d_in[9];

    float* out        = (float*)d_out;
    float* context    = out;
    float* alignments = out + B * DM;
    float* new_state  = out + B * DM + B * T;

    char* ws = (char*)d_ws;
    float*          pqp     = (float*)ws;                       // 256 KB
    unsigned short* wsplit  = (unsigned short*)(ws + 262144);   // 128 KB (hi only)
    unsigned short* CWt     = (unsigned short*)(ws + 524288);   // 8 KB
    float*          energy  = (float*)(ws + 532480);            // 512 KB
    float*          partial = (float*)(ws + 1056768);           // 1 MB

    prep_kernel<<<dim3(4 * B + DM + 32), 128, 0, stream>>>(query, Wq, Wmem, conv_k, Wloc, pqp, wsplit, CWt);
    energy_mfma<<<dim3(B * (T / 128)), 256, 0, stream>>>(memory, state, pqp, wsplit, CWt, v_w, v_b, energy);
    softmax_context_kernel<<<dim3(B, TSEG), 256, 0, stream>>>(energy, state, memory, alignments, new_state, partial);
    context_reduce_kernel<<<dim3(B), 256, 0, stream>>>(partial, context);
}

// Round 9
// 121.647 us; speedup vs baseline: 1.4091x; 1.4091x over previous
//
#include <hip/hip_runtime.h>
#include <math.h>

#define B  128
#define T  1024
#define DM 512
#define DQ 1024
#define DA 128
#define F  32
#define KW 31

typedef short s16x8 __attribute__((ext_vector_type(8)));
typedef float f32x4 __attribute__((ext_vector_type(4)));
typedef unsigned int u32;
typedef u32 u32x4 __attribute__((ext_vector_type(4)));
typedef __attribute__((address_space(1))) const unsigned int gu32;
typedef __attribute__((address_space(3))) unsigned int lu32;

__device__ __forceinline__ unsigned short f2bf(float f) {   // RNE
    u32 u = __builtin_bit_cast(u32, f);
    u32 r = u + 0x7FFFu + ((u >> 16) & 1u);
    return (unsigned short)(r >> 16);
}
__device__ __forceinline__ float bf2f(unsigned short h) {
    u32 u = ((u32)h) << 16;
    return __builtin_bit_cast(float, u);
}
__device__ __forceinline__ float fast_tanh(float x) {
    float ax = fabsf(x);
    float e = __expf(-2.0f * ax);
    float t = 1.0f - 2.0f * e / (1.0f + e);
    return copysignf(t, x);
}

// truncate-split: hi = f with low 16 mantissa bits zeroed, lo = f - hi (exact), lo trunc.
__device__ __forceinline__ void trunc_split_pack(f32x4 a, f32x4 b, s16x8& hi, s16x8& lo) {
    u32x4 hw, lw;
    #pragma unroll
    for (int p = 0; p < 4; ++p) {
        float f0 = (p < 2) ? a[2 * p] : b[2 * p - 4];
        float f1 = (p < 2) ? a[2 * p + 1] : b[2 * p - 3];
        u32 u0 = __builtin_bit_cast(u32, f0);
        u32 u1 = __builtin_bit_cast(u32, f1);
        u32 t0 = u0 & 0xFFFF0000u;
        u32 t1 = u1 & 0xFFFF0000u;
        float l0 = f0 - __builtin_bit_cast(float, t0);
        float l1 = f1 - __builtin_bit_cast(float, t1);
        hw[p] = (u0 >> 16) | t1;
        lw[p] = (__builtin_bit_cast(u32, l0) >> 16) | (__builtin_bit_cast(u32, l1) & 0xFFFF0000u);
    }
    hi = __builtin_bit_cast(s16x8, hw);
    lo = __builtin_bit_cast(s16x8, lw);
}

// ---------------- prep: pq partials, Wmem hi (transposed+swizzled), CWt ----------------
__global__ __launch_bounds__(128) void prep_kernel(
        const float* __restrict__ query, const float* __restrict__ Wq,
        const float* __restrict__ Wmem, const float* __restrict__ conv_k,
        const float* __restrict__ Wloc,
        float* __restrict__ pqp, unsigned short* __restrict__ wsplit,
        unsigned short* __restrict__ CWt) {
    int a = threadIdx.x;
    int blk = blockIdx.x;
    if (blk < 4 * B) {
        int b = blk >> 2, q = blk & 3;
        const float* qp = query + b * DQ + q * 256;
        const float* wp = Wq + (size_t)(q * 256) * DA + a;
        float s = 0.f;
        #pragma unroll 4
        for (int i = 0; i < 256; ++i) s += qp[i] * wp[(size_t)i * DA];
        pqp[(q * B + b) * DA + a] = s;
    } else if (blk < 4 * B + DM) {
        int k = blk - 4 * B;
        unsigned short hi = f2bf(Wmem[k * DA + a]);   // B_hi only
        int c = k >> 6;
        int es = (k & 63) ^ ((a & 7) << 3);           // pre-swizzled for LDS reads
        wsplit[c * 8192 + a * 64 + es] = hi;          // [chunk][a][k'] 16 KB per chunk
    } else {
        int k = blk - (4 * B + DM);                   // 0..31 (row 31 = zero pad)
        float s = 0.f;
        if (k < KW) {
            #pragma unroll
            for (int f = 0; f < F; ++f) s += conv_k[k * F + f] * Wloc[f * DA + a];
        }
        CWt[a * 32 + k] = f2bf(s);                    // [a][k] contiguous
    }
}

// ---------------- energy (R6 core) + fused per-wave online-softmax context partial ----------------
__global__ __launch_bounds__(256, 4) void energy_mfma(
        const float* __restrict__ memory, const float* __restrict__ state,
        const float* __restrict__ pqp, const unsigned short* __restrict__ wsplit,
        const unsigned short* __restrict__ CWt, const float* __restrict__ v_w,
        const float* __restrict__ v_b, float* __restrict__ energy,
        float* __restrict__ pctx, float2* __restrict__ ms) {
    __shared__ unsigned short Wlds[8192];    // 16 KB: B_hi for one chunk
    __shared__ unsigned short cwlds[4096];   // 8 KB conv weights
    __shared__ float stl[160];
    __shared__ float pql[DA];
    __shared__ float vwl[DA];
    __shared__ float el[128];                // tile energies for epilogue

    int tid = threadIdx.x;
    int w = tid >> 6, l = tid & 63, r = l & 15, g = l >> 4;
    int b  = blockIdx.x >> 3;
    int tile = blockIdx.x & 7;
    int t0 = tile << 7;                      // 128-row tile

    for (int i = tid; i < 160; i += 256) {
        int t = t0 - 15 + i;
        stl[i] = (i < 159 && t >= 0 && t < T) ? state[b * T + t] : 0.f;
    }
    if (tid < DA) {
        float s = 0.f;
        #pragma unroll
        for (int q = 0; q < 4; ++q) s += pqp[(q * B + b) * DA + tid];
        pql[tid] = s;
        vwl[tid] = v_w[tid];
    }

    // stage conv weights once (drained by the first chunk's barrier)
    #pragma unroll
    for (int rd = 0; rd < 2; ++rd)
        __builtin_amdgcn_global_load_lds((gu32*)(CWt + rd * 2048 + tid * 8),
                                         (lu32*)(cwlds + (w << 9) + rd * 2048), 16, 0, 0);

    f32x4 acc0[8], acc1[8];
    #pragma unroll
    for (int nt = 0; nt < 8; ++nt) {
        acc0[nt] = (f32x4){0.f, 0.f, 0.f, 0.f};
        acc1[nt] = (f32x4){0.f, 0.f, 0.f, 0.f};
    }

    const int swz8 = (r & 7) << 3;
    const size_t arow = ((size_t)(b * T + t0 + w * 32 + r)) * DM;

    for (int c = 0; c < 8; ++c) {
        __syncthreads();                      // previous chunk's ds_reads complete
        {   // stage B_hi chunk: 16 KB, 4 x 16B per thread
            const unsigned short* src = wsplit + (size_t)c * 8192 + tid * 8;
            #pragma unroll
            for (int rd = 0; rd < 4; ++rd)
                __builtin_amdgcn_global_load_lds((gu32*)(src + rd * 2048),
                                                 (lu32*)(Wlds + (w << 9) + rd * 2048),
                                                 16, 0, 0);
        }
        __syncthreads();                      // staged (vmcnt drained by barrier)

        const float* Ab = memory + arow + c * 64;
        #pragma unroll
        for (int kk = 0; kk < 2; ++kk) {
            const float* p0 = Ab + kk * 32 + g * 8;
            f32x4 f00 = *(const f32x4*)p0;
            f32x4 f01 = *(const f32x4*)(p0 + 4);
            const float* p1 = p0 + 16 * DM;
            f32x4 f10 = *(const f32x4*)p1;
            f32x4 f11 = *(const f32x4*)(p1 + 4);
            s16x8 Ah0, Al0, Ah1, Al1;
            trunc_split_pack(f00, f01, Ah0, Al0);
            trunc_split_pack(f10, f11, Ah1, Al1);
            int off = (kk * 32 + g * 8) ^ swz8;
            #pragma unroll
            for (int nt = 0; nt < 8; ++nt) {
                const unsigned short* bp = Wlds + (nt * 16 + r) * 64 + off;
                s16x8 Bh = *(const s16x8*)bp;
                acc0[nt] = __builtin_amdgcn_mfma_f32_16x16x32_bf16(Ah0, Bh, acc0[nt], 0, 0, 0);
                acc0[nt] = __builtin_amdgcn_mfma_f32_16x16x32_bf16(Al0, Bh, acc0[nt], 0, 0, 0);
                acc1[nt] = __builtin_amdgcn_mfma_f32_16x16x32_bf16(Ah1, Bh, acc1[nt], 0, 0, 0);
                acc1[nt] = __builtin_amdgcn_mfma_f32_16x16x32_bf16(Al1, Bh, acc1[nt], 0, 0, 0);
            }
        }
    }

    // ---- fold loc conv into the accumulators ----
    s16x8 st0, st1;
    {
        int base0 = w * 32 + r + g * 8;
        #pragma unroll
        for (int j = 0; j < 8; ++j) {
            st0[j] = (short)f2bf(stl[base0 + j]);
            st1[j] = (short)f2bf(stl[base0 + 16 + j]);
        }
    }
    #pragma unroll
    for (int nt = 0; nt < 8; ++nt) {
        const unsigned short* cp = cwlds + (nt * 16 + r) * 32 + g * 8;
        s16x8 cw = *(const s16x8*)cp;
        acc0[nt] = __builtin_amdgcn_mfma_f32_16x16x32_bf16(st0, cw, acc0[nt], 0, 0, 0);
        acc1[nt] = __builtin_amdgcn_mfma_f32_16x16x32_bf16(st1, cw, acc1[nt], 0, 0, 0);
    }

    // ---- epilogue: +pq, tanh, .v_w, 16-lane reduce, write energy (global + LDS) ----
    float vb = *v_b;
    #pragma unroll
    for (int sub = 0; sub < 2; ++sub) {
        #pragma unroll
        for (int reg = 0; reg < 4; ++reg) {
            float p = 0.f;
            #pragma unroll
            for (int nt = 0; nt < 8; ++nt) {
                int col = nt * 16 + r;
                float v = (sub == 0) ? acc0[nt][reg] : acc1[nt][reg];
                p += fast_tanh(v + pql[col]) * vwl[col];
            }
            p += __shfl_xor(p, 1, 16);
            p += __shfl_xor(p, 2, 16);
            p += __shfl_xor(p, 4, 16);
            p += __shfl_xor(p, 8, 16);
            if (r == 0) {
                int tl = w * 32 + sub * 16 + g * 4 + reg;
                energy[b * T + t0 + tl] = p + vb;
                el[tl] = p + vb;
            }
        }
    }
    __syncthreads();

    // ---- per-wave online-softmax context partial over this wave's 32 rows (L2-hot re-read) ----
    float m_w = -1e30f;
    #pragma unroll
    for (int t = 0; t < 32; ++t) m_w = fmaxf(m_w, el[w * 32 + t]);
    float s_w = 0.f;
    f32x4 c0 = (f32x4){0.f, 0.f, 0.f, 0.f};
    f32x4 c1 = (f32x4){0.f, 0.f, 0.f, 0.f};
    const float* mb = memory + ((size_t)(b * T + t0 + w * 32)) * DM + l * 8;
    #pragma unroll 4
    for (int t = 0; t < 32; ++t) {
        float pw = __expf(el[w * 32 + t] - m_w);
        s_w += pw;
        f32x4 v0 = *(const f32x4*)(mb + (size_t)t * DM);
        f32x4 v1 = *(const f32x4*)(mb + (size_t)t * DM + 4);
        c0 += pw * v0;
        c1 += pw * v1;
    }
    float* po = pctx + ((size_t)(tile * 4 + w) * B + b) * DM + l * 8;
    *(f32x4*)po = c0;
    *(f32x4*)(po + 4) = c1;
    if (l == 0) ms[(tile * 4 + w) * B + b] = make_float2(m_w, s_w);
}

// ---------------- finalize: global softmax stats, alignments/new_state, context reduce ----------------
__global__ __launch_bounds__(256) void finalize_kernel(
        const float* __restrict__ energy, const float* __restrict__ state,
        const float2* __restrict__ ms, const float* __restrict__ pctx,
        float* __restrict__ alignments, float* __restrict__ new_state,
        float* __restrict__ context) {
    int b = blockIdx.x, tid = threadIdx.x;
    float m = -1e30f;
    #pragma unroll
    for (int i = 0; i < 32; ++i) m = fmaxf(m, ms[i * B + b].x);
    float sc[32];
    float S = 0.f;
    #pragma unroll
    for (int i = 0; i < 32; ++i) {
        float2 v = ms[i * B + b];
        float e = __expf(v.x - m);
        sc[i] = e;
        S += e * v.y;
    }
    float invS = 1.0f / S;

    // alignments + new_state (4 per thread)
    f32x4 ev = ((const f32x4*)(energy + b * T))[tid];
    f32x4 a4;
    a4[0] = __expf(ev[0] - m) * invS;
    a4[1] = __expf(ev[1] - m) * invS;
    a4[2] = __expf(ev[2] - m) * invS;
    a4[3] = __expf(ev[3] - m) * invS;
    ((f32x4*)(alignments + b * T))[tid] = a4;
    f32x4 st4 = ((const f32x4*)(state + b * T))[tid];
    ((f32x4*)(new_state + b * T))[tid] = a4 + st4;

    // context (2 cols per thread, coalesced)
    #pragma unroll
    for (int j = 0; j < 2; ++j) {
        int d = tid + j * 256;
        float c = 0.f;
        #pragma unroll 8
        for (int i = 0; i < 32; ++i)
            c += sc[i] * pctx[((size_t)i * B + b) * DM + d];
        context[b * DM + d] = c * invS;
    }
}

extern "C" void kernel_launch(void* const* d_in, const int* in_sizes, int n_in,
                              void* d_out, int out_size, void* d_ws, size_t ws_size,
                              hipStream_t stream) {
    const float* query  = (const float*)d_in[0];
    const float* state  = (const float*)d_in[1];
    const float* memory = (const float*)d_in[3];
    const float* Wq     = (const float*)d_in[4];
    const float* Wmem   = (const float*)d_in[5];
    const float* conv_k = (const float*)d_in[6];
    const float* Wloc   = (const float*)d_in[7];
    const float* v_w    = (const float*)d_in[8];
    const float* v_b    = (const float*)d_in[9];

    float* out        = (float*)d_out;
    float* context    = out;
    float* alignments = out + B * DM;
    float* new_state  = out + B * DM + B * T;

    char* ws = (char*)d_ws;
    float*          pqp     = (float*)ws;                       // 256 KB
    unsigned short* wsplit  = (unsigned short*)(ws + 262144);   // 128 KB (hi only)
    unsigned short* CWt     = (unsigned short*)(ws + 524288);   // 8 KB
    float*          energy  = (float*)(ws + 532480);            // 512 KB
    float*          pctx    = (float*)(ws + 1056768);           // 8 MB
    float2*         ms      = (float2*)(ws + 1056768 + 8388608); // 32 KB

    prep_kernel<<<dim3(4 * B + DM + 32), 128, 0, stream>>>(query, Wq, Wmem, conv_k, Wloc, pqp, wsplit, CWt);
    energy_mfma<<<dim3(B * (T / 128)), 256, 0, stream>>>(memory, state, pqp, wsplit, CWt, v_w, v_b, energy, pctx, ms);
    finalize_kernel<<<dim3(B), 256, 0, stream>>>(energy, state, ms, pctx, alignments, new_state, context);
}

// Round 10
// 120.562 us; speedup vs baseline: 1.4218x; 1.0090x over previous
//
#include <hip/hip_runtime.h>
#include <math.h>

#define B  128
#define T  1024
#define DM 512
#define DQ 1024
#define DA 128
#define F  32
#define KW 31

typedef short s16x8 __attribute__((ext_vector_type(8)));
typedef float f32x4 __attribute__((ext_vector_type(4)));
typedef unsigned int u32;
typedef u32 u32x4 __attribute__((ext_vector_type(4)));
typedef __attribute__((address_space(1))) const unsigned int gu32;
typedef __attribute__((address_space(3))) unsigned int lu32;

__device__ __forceinline__ unsigned short f2bf(float f) {   // RNE
    u32 u = __builtin_bit_cast(u32, f);
    u32 r = u + 0x7FFFu + ((u >> 16) & 1u);
    return (unsigned short)(r >> 16);
}
__device__ __forceinline__ float bf2f(unsigned short h) {
    u32 u = ((u32)h) << 16;
    return __builtin_bit_cast(float, u);
}
__device__ __forceinline__ float fast_tanh(float x) {
    float ax = fabsf(x);
    float e = __expf(-2.0f * ax);
    float t = 1.0f - 2.0f * e / (1.0f + e);
    return copysignf(t, x);
}

// truncate-split: hi = f with low 16 mantissa bits zeroed, lo = f - hi (exact), lo trunc.
__device__ __forceinline__ void trunc_split_pack(f32x4 a, f32x4 b, s16x8& hi, s16x8& lo) {
    u32x4 hw, lw;
    #pragma unroll
    for (int p = 0; p < 4; ++p) {
        float f0 = (p < 2) ? a[2 * p] : b[2 * p - 4];
        float f1 = (p < 2) ? a[2 * p + 1] : b[2 * p - 3];
        u32 u0 = __builtin_bit_cast(u32, f0);
        u32 u1 = __builtin_bit_cast(u32, f1);
        u32 t0 = u0 & 0xFFFF0000u;
        u32 t1 = u1 & 0xFFFF0000u;
        float l0 = f0 - __builtin_bit_cast(float, t0);
        float l1 = f1 - __builtin_bit_cast(float, t1);
        hw[p] = (u0 >> 16) | t1;
        lw[p] = (__builtin_bit_cast(u32, l0) >> 16) | (__builtin_bit_cast(u32, l1) & 0xFFFF0000u);
    }
    hi = __builtin_bit_cast(s16x8, hw);
    lo = __builtin_bit_cast(s16x8, lw);
}

// ---------------- prep: pq partials (8-way DQ split), Wmem hi (transposed+swizzled), CWt ----------------
__global__ __launch_bounds__(128) void prep_kernel(
        const float* __restrict__ query, const float* __restrict__ Wq,
        const float* __restrict__ Wmem, const float* __restrict__ conv_k,
        const float* __restrict__ Wloc,
        float* __restrict__ pqp, unsigned short* __restrict__ wsplit,
        unsigned short* __restrict__ CWt) {
    int a = threadIdx.x;
    int blk = blockIdx.x;
    if (blk < 8 * B) {
        int b = blk >> 3, q = blk & 7;
        const float* qp = query + b * DQ + q * 128;
        const float* wp = Wq + (size_t)(q * 128) * DA + a;
        float s = 0.f;
        #pragma unroll 4
        for (int i = 0; i < 128; ++i) s += qp[i] * wp[(size_t)i * DA];
        pqp[(q * B + b) * DA + a] = s;
    } else if (blk < 8 * B + DM) {
        int k = blk - 8 * B;
        unsigned short hi = f2bf(Wmem[k * DA + a]);   // B_hi only
        int c = k >> 6;
        int es = (k & 63) ^ ((a & 7) << 3);           // pre-swizzled for LDS reads
        wsplit[c * 8192 + a * 64 + es] = hi;          // [chunk][a][k'] 16 KB per chunk
    } else {
        int k = blk - (8 * B + DM);                   // 0..31 (row 31 = zero pad)
        float s = 0.f;
        if (k < KW) {
            #pragma unroll
            for (int f = 0; f < F; ++f) s += conv_k[k * F + f] * Wloc[f * DA + a];
        }
        CWt[a * 32 + k] = f2bf(s);                    // [a][k] contiguous
    }
}

// ---------------- energy (R9 core + A-register prefetch) + fused context partial ----------------
__global__ __launch_bounds__(256, 3) void energy_mfma(
        const float* __restrict__ memory, const float* __restrict__ state,
        const float* __restrict__ pqp, const unsigned short* __restrict__ wsplit,
        const unsigned short* __restrict__ CWt, const float* __restrict__ v_w,
        const float* __restrict__ v_b, float* __restrict__ energy,
        float* __restrict__ pctx, float2* __restrict__ ms) {
    __shared__ unsigned short Wlds[8192];    // 16 KB: B_hi for one chunk
    __shared__ unsigned short cwlds[4096];   // 8 KB conv weights
    __shared__ float stl[160];
    __shared__ float pql[DA];
    __shared__ float vwl[DA];
    __shared__ float el[128];                // tile energies for epilogue

    int tid = threadIdx.x;
    int w = tid >> 6, l = tid & 63, r = l & 15, g = l >> 4;
    int b  = blockIdx.x >> 3;
    int tile = blockIdx.x & 7;
    int t0 = tile << 7;                      // 128-row tile

    for (int i = tid; i < 160; i += 256) {
        int t = t0 - 15 + i;
        stl[i] = (i < 159 && t >= 0 && t < T) ? state[b * T + t] : 0.f;
    }
    if (tid < DA) {
        float s = 0.f;
        #pragma unroll
        for (int q = 0; q < 8; ++q) s += pqp[(q * B + b) * DA + tid];
        pql[tid] = s;
        vwl[tid] = v_w[tid];
    }

    // stage conv weights once (drained by the first chunk's barrier)
    #pragma unroll
    for (int rd = 0; rd < 2; ++rd)
        __builtin_amdgcn_global_load_lds((gu32*)(CWt + rd * 2048 + tid * 8),
                                         (lu32*)(cwlds + (w << 9) + rd * 2048), 16, 0, 0);

    f32x4 acc0[8], acc1[8];
    #pragma unroll
    for (int nt = 0; nt < 8; ++nt) {
        acc0[nt] = (f32x4){0.f, 0.f, 0.f, 0.f};
        acc1[nt] = (f32x4){0.f, 0.f, 0.f, 0.f};
    }

    const int swz8 = (r & 7) << 3;
    const size_t arow = ((size_t)(b * T + t0 + w * 32 + r)) * DM;
    const float* Abase = memory + arow + g * 8;

    f32x4 rA[8], rAn[8];
    {   // prologue: A(0) -> regs
        const float* p = Abase;
        #pragma unroll
        for (int kk = 0; kk < 2; ++kk) {
            rA[kk * 4 + 0] = *(const f32x4*)(p + kk * 32);
            rA[kk * 4 + 1] = *(const f32x4*)(p + kk * 32 + 4);
            rA[kk * 4 + 2] = *(const f32x4*)(p + kk * 32 + 16 * DM);
            rA[kk * 4 + 3] = *(const f32x4*)(p + kk * 32 + 16 * DM + 4);
        }
    }

    for (int c = 0; c < 8; ++c) {
        __syncthreads();                      // previous chunk's ds_reads complete
        {   // stage B_hi chunk: 16 KB (L2-hot), 4 x 16B per thread
            const unsigned short* src = wsplit + (size_t)c * 8192 + tid * 8;
            #pragma unroll
            for (int rd = 0; rd < 4; ++rd)
                __builtin_amdgcn_global_load_lds((gu32*)(src + rd * 2048),
                                                 (lu32*)(Wlds + (w << 9) + rd * 2048),
                                                 16, 0, 0);
        }
        __syncthreads();                      // staged (vmcnt drained by barrier)

        if (c < 7) {   // prefetch next chunk's A: overlaps this chunk's compute
            const float* p = Abase + (c + 1) * 64;
            #pragma unroll
            for (int kk = 0; kk < 2; ++kk) {
                rAn[kk * 4 + 0] = *(const f32x4*)(p + kk * 32);
                rAn[kk * 4 + 1] = *(const f32x4*)(p + kk * 32 + 4);
                rAn[kk * 4 + 2] = *(const f32x4*)(p + kk * 32 + 16 * DM);
                rAn[kk * 4 + 3] = *(const f32x4*)(p + kk * 32 + 16 * DM + 4);
            }
        }

        #pragma unroll
        for (int kk = 0; kk < 2; ++kk) {
            s16x8 Ah0, Al0, Ah1, Al1;
            trunc_split_pack(rA[kk * 4 + 0], rA[kk * 4 + 1], Ah0, Al0);
            trunc_split_pack(rA[kk * 4 + 2], rA[kk * 4 + 3], Ah1, Al1);
            int off = (kk * 32 + g * 8) ^ swz8;
            #pragma unroll
            for (int nt = 0; nt < 8; ++nt) {
                const unsigned short* bp = Wlds + (nt * 16 + r) * 64 + off;
                s16x8 Bh = *(const s16x8*)bp;
                acc0[nt] = __builtin_amdgcn_mfma_f32_16x16x32_bf16(Ah0, Bh, acc0[nt], 0, 0, 0);
                acc0[nt] = __builtin_amdgcn_mfma_f32_16x16x32_bf16(Al0, Bh, acc0[nt], 0, 0, 0);
                acc1[nt] = __builtin_amdgcn_mfma_f32_16x16x32_bf16(Ah1, Bh, acc1[nt], 0, 0, 0);
                acc1[nt] = __builtin_amdgcn_mfma_f32_16x16x32_bf16(Al1, Bh, acc1[nt], 0, 0, 0);
            }
        }
        #pragma unroll
        for (int j = 0; j < 8; ++j) rA[j] = rAn[j];
    }

    // ---- fold loc conv into the accumulators ----
    s16x8 st0, st1;
    {
        int base0 = w * 32 + r + g * 8;
        #pragma unroll
        for (int j = 0; j < 8; ++j) {
            st0[j] = (short)f2bf(stl[base0 + j]);
            st1[j] = (short)f2bf(stl[base0 + 16 + j]);
        }
    }
    #pragma unroll
    for (int nt = 0; nt < 8; ++nt) {
        const unsigned short* cp = cwlds + (nt * 16 + r) * 32 + g * 8;
        s16x8 cw = *(const s16x8*)cp;
        acc0[nt] = __builtin_amdgcn_mfma_f32_16x16x32_bf16(st0, cw, acc0[nt], 0, 0, 0);
        acc1[nt] = __builtin_amdgcn_mfma_f32_16x16x32_bf16(st1, cw, acc1[nt], 0, 0, 0);
    }

    // ---- epilogue: +pq, tanh, .v_w, 16-lane reduce, write energy (global + LDS) ----
    float vb = *v_b;
    #pragma unroll
    for (int sub = 0; sub < 2; ++sub) {
        #pragma unroll
        for (int reg = 0; reg < 4; ++reg) {
            float p = 0.f;
            #pragma unroll
            for (int nt = 0; nt < 8; ++nt) {
                int col = nt * 16 + r;
                float v = (sub == 0) ? acc0[nt][reg] : acc1[nt][reg];
                p += fast_tanh(v + pql[col]) * vwl[col];
            }
            p += __shfl_xor(p, 1, 16);
            p += __shfl_xor(p, 2, 16);
            p += __shfl_xor(p, 4, 16);
            p += __shfl_xor(p, 8, 16);
            if (r == 0) {
                int tl = w * 32 + sub * 16 + g * 4 + reg;
                energy[b * T + t0 + tl] = p + vb;
                el[tl] = p + vb;
            }
        }
    }
    __syncthreads();

    // ---- per-wave online-softmax context partial over this wave's 32 rows ----
    float m_w = -1e30f;
    #pragma unroll
    for (int t = 0; t < 32; ++t) m_w = fmaxf(m_w, el[w * 32 + t]);
    float s_w = 0.f;
    f32x4 c0 = (f32x4){0.f, 0.f, 0.f, 0.f};
    f32x4 c1 = (f32x4){0.f, 0.f, 0.f, 0.f};
    const float* mb = memory + ((size_t)(b * T + t0 + w * 32)) * DM + l * 8;
    #pragma unroll 4
    for (int t = 0; t < 32; ++t) {
        float pw = __expf(el[w * 32 + t] - m_w);
        s_w += pw;
        f32x4 v0 = *(const f32x4*)(mb + (size_t)t * DM);
        f32x4 v1 = *(const f32x4*)(mb + (size_t)t * DM + 4);
        c0 += pw * v0;
        c1 += pw * v1;
    }
    float* po = pctx + ((size_t)(tile * 4 + w) * B + b) * DM + l * 8;
    *(f32x4*)po = c0;
    *(f32x4*)(po + 4) = c1;
    if (l == 0) ms[(tile * 4 + w) * B + b] = make_float2(m_w, s_w);
}

// ---------------- finalize: global softmax stats, alignments/new_state, context reduce ----------------
__global__ __launch_bounds__(256) void finalize_kernel(
        const float* __restrict__ energy, const float* __restrict__ state,
        const float2* __restrict__ ms, const float* __restrict__ pctx,
        float* __restrict__ alignments, float* __restrict__ new_state,
        float* __restrict__ context) {
    int b = blockIdx.x, tid = threadIdx.x;
    float m = -1e30f;
    #pragma unroll
    for (int i = 0; i < 32; ++i) m = fmaxf(m, ms[i * B + b].x);
    float sc[32];
    float S = 0.f;
    #pragma unroll
    for (int i = 0; i < 32; ++i) {
        float2 v = ms[i * B + b];
        float e = __expf(v.x - m);
        sc[i] = e;
        S += e * v.y;
    }
    float invS = 1.0f / S;

    // alignments + new_state (4 per thread)
    f32x4 ev = ((const f32x4*)(energy + b * T))[tid];
    f32x4 a4;
    a4[0] = __expf(ev[0] - m) * invS;
    a4[1] = __expf(ev[1] - m) * invS;
    a4[2] = __expf(ev[2] - m) * invS;
    a4[3] = __expf(ev[3] - m) * invS;
    ((f32x4*)(alignments + b * T))[tid] = a4;
    f32x4 st4 = ((const f32x4*)(state + b * T))[tid];
    ((f32x4*)(new_state + b * T))[tid] = a4 + st4;

    // context (2 cols per thread, coalesced)
    #pragma unroll
    for (int j = 0; j < 2; ++j) {
        int d = tid + j * 256;
        float c = 0.f;
        #pragma unroll 8
        for (int i = 0; i < 32; ++i)
            c += sc[i] * pctx[((size_t)i * B + b) * DM + d];
        context[b * DM + d] = c * invS;
    }
}

extern "C" void kernel_launch(void* const* d_in, const int* in_sizes, int n_in,
                              void* d_out, int out_size, void* d_ws, size_t ws_size,
                              hipStream_t stream) {
    const float* query  = (const float*)d_in[0];
    const float* state  = (const float*)d_in[1];
    const float* memory = (const float*)d_in[3];
    const float* Wq     = (const float*)d_in[4];
    const float* Wmem   = (const float*)d_in[5];
    const float* conv_k = (const float*)d_in[6];
    const float* Wloc   = (const float*)d_in[7];
    const float* v_w    = (const float*)d_in[8];
    const float* v_b    = (const float*)d_in[9];

    float* out        = (float*)d_out;
    float* context    = out;
    float* alignments = out + B * DM;
    float* new_state  = out + B * DM + B * T;

    char* ws = (char*)d_ws;
    float*          pqp     = (float*)ws;                        // 512 KB (8 partials)
    unsigned short* wsplit  = (unsigned short*)(ws + 524288);    // 128 KB (hi only)
    unsigned short* CWt     = (unsigned short*)(ws + 655360);    // 8 KB
    float*          energy  = (float*)(ws + 663552);             // 512 KB
    float*          pctx    = (float*)(ws + 1187840);            // 8 MB
    float2*         ms      = (float2*)(ws + 1187840 + 8388608); // 32 KB

    prep_kernel<<<dim3(8 * B + DM + 32), 128, 0, stream>>>(query, Wq, Wmem, conv_k, Wloc, pqp, wsplit, CWt);
    energy_mfma<<<dim3(B * (T / 128)), 256, 0, stream>>>(memory, state, pqp, wsplit, CWt, v_w, v_b, energy, pctx, ms);
    finalize_kernel<<<dim3(B), 256, 0, stream>>>(energy, state, ms, pctx, alignments, new_state, context);
}